// Round 1
// baseline (1231.400 us; speedup 1.0000x reference)
//
#include <hip/hip_runtime.h>
#include <hip/hip_bf16.h>

#define T_SEQ 2048
#define BATCH 2
#define CDIM  2048
#define NH    16
#define NKV   4
#define DH    128

typedef __attribute__((ext_vector_type(8))) short bfrag;   // 8 bf16 (4 VGPRs)
typedef __attribute__((ext_vector_type(4))) float ffrag;   // 4 f32 acc
typedef __hip_bfloat16 bf16;

// ---------------- fp32 -> bf16 cast ----------------
__global__ void cast_f2b(const float* __restrict__ src, bf16* __restrict__ dst, int n) {
    int i = blockIdx.x * blockDim.x + threadIdx.x;
    if (i < n) dst[i] = __float2bfloat16(src[i]);
}

// ---------------- GEMM: out[m][n] = sum_k A[m][k] * W[n][k] ----------------
// MODE 0: Q GEMM  -> out0 = q   laid out (B, NH, T, DH) bf16
// MODE 1: KV GEMM -> out0 = k   (B, NKV, T, DH) bf16 ; out1 = v^T (B, NKV, DH, T) bf16
// MODE 2: proj    -> outf fp32 (B*T, C)
template<int MODE>
__global__ __launch_bounds__(256) void gemm_k(
    const bf16* __restrict__ A, const bf16* __restrict__ W,
    bf16* __restrict__ out0, bf16* __restrict__ out1, float* __restrict__ outf)
{
    const int lane = threadIdx.x & 63;
    const int wave = threadIdx.x >> 6;
    const int m0 = blockIdx.x * 64 + wave * 16;
    const int n0 = blockIdx.y * 64;
    const int lr = lane & 15;          // row within 16-tile
    const int lk = (lane >> 4) * 8;    // k offset within 32-chunk

    const bf16* arow = A + (size_t)(m0 + lr) * CDIM + lk;
    const bf16* wrow = W + (size_t)(n0 + lr) * CDIM + lk;

    ffrag acc[4] = {};
    for (int kk = 0; kk < CDIM; kk += 32) {
        bfrag a = *(const bfrag*)(arow + kk);
        #pragma unroll
        for (int j = 0; j < 4; ++j) {
            bfrag b = *(const bfrag*)(wrow + (size_t)j * 16 * CDIM + kk);
            acc[j] = __builtin_amdgcn_mfma_f32_16x16x32_bf16(a, b, acc[j], 0, 0, 0);
        }
    }

    const int rbase = m0 + (lane >> 4) * 4;  // C/D: row=(lane>>4)*4+i, col=lane&15
    #pragma unroll
    for (int j = 0; j < 4; ++j) {
        int n = n0 + j * 16 + lr;
        #pragma unroll
        for (int i = 0; i < 4; ++i) {
            int m = rbase + i;
            float v = acc[j][i];
            if (MODE == 0) {
                int b = m >> 11, t = m & (T_SEQ - 1);
                int h = n >> 7, d = n & (DH - 1);
                out0[(((size_t)(b * NH + h) * T_SEQ + t) << 7) + d] = __float2bfloat16(v);
            } else if (MODE == 1) {
                int b = m >> 11, t = m & (T_SEQ - 1);
                if (n < NKV * DH) {
                    int h = n >> 7, d = n & (DH - 1);
                    out0[(((size_t)(b * NKV + h) * T_SEQ + t) << 7) + d] = __float2bfloat16(v);
                } else {
                    int n2 = n - NKV * DH;
                    int h = n2 >> 7, d = n2 & (DH - 1);
                    // v transposed: (B, NKV, DH, T)
                    out1[(((size_t)(b * NKV + h) * DH + d) << 11) + t] = __float2bfloat16(v);
                }
            } else {
                outf[(size_t)m * CDIM + n] = v;
            }
        }
    }
    if (MODE == 2 && blockIdx.x == 0 && blockIdx.y == 0 && threadIdx.x == 0) {
        outf[(size_t)BATCH * T_SEQ * CDIM] = 0.0f;   // reference's second output: 0.0
    }
}

// ---------------- RMSNorm + rotary (angle indexed by HEAD per reference bug) ----------------
__global__ __launch_bounds__(64) void normrope_k(bf16* __restrict__ buf, int nheads) {
    const int idx = blockIdx.x;                 // (b*nheads + h)*T + t
    const int h = (idx >> 11) % nheads;         // T = 2048 = 2^11
    bf16* row = buf + (size_t)idx * DH;
    const int d = threadIdx.x;                  // 0..63, pairs (d, d+64)
    float x1 = __bfloat162float(row[d]);
    float x2 = __bfloat162float(row[d + 64]);
    float ss = x1 * x1 + x2 * x2;
    #pragma unroll
    for (int off = 32; off; off >>= 1) ss += __shfl_xor(ss, off);
    float r = rsqrtf(ss * (1.0f / 128.0f) + 1.1920929e-07f);
    x1 *= r; x2 *= r;
    float freq = (d < 32) ? exp2f(-10.0f * (float)d * (1.0f / 31.0f)) : 0.0f;
    float th = (float)h * freq;   // NOTE: head index, not position — replicates reference
    float c = cosf(th), s = sinf(th);
    float y1 = x1 * c + x2 * s;
    float y2 = -x1 * s + x2 * c;
    row[d]      = __float2bfloat16(y1);
    row[d + 64] = __float2bfloat16(y2);
}

// ---------------- Flash attention: 1 wave per (b, h, 16-row q-tile) ----------------
__global__ __launch_bounds__(64) void attn_k(const bf16* __restrict__ Q, const bf16* __restrict__ K,
                                             const bf16* __restrict__ VT, bf16* __restrict__ Y)
{
    const int lane = threadIdx.x;
    const int qt = blockIdx.x, h = blockIdx.y, b = blockIdx.z;
    const int q0 = qt * 16;
    const bf16* Qb = Q  + (size_t)(b * NH  + h)        * T_SEQ * DH;
    const bf16* Kb = K  + (size_t)(b * NKV + (h >> 2)) * T_SEQ * DH;
    const bf16* Vb = VT + (size_t)(b * NKV + (h >> 2)) * DH * T_SEQ;
    const int lr = lane & 15;
    const int lk = (lane >> 4) * 8;

    bfrag qf[4];
    #pragma unroll
    for (int dc = 0; dc < 4; ++dc)
        qf[dc] = *(const bfrag*)(Qb + (size_t)(q0 + lr) * DH + dc * 32 + lk);

    float m_i[4], l_i[4];
    #pragma unroll
    for (int i = 0; i < 4; ++i) { m_i[i] = -1e30f; l_i[i] = 0.0f; }
    ffrag o[8] = {};

    __shared__ __align__(16) bf16 Pl[16 * 32];
    const float scale = 0.08838834764831845f;  // 1/sqrt(128)
    const int nchunk = (q0 + 16 + 31) >> 5;

    for (int cc = 0; cc < nchunk; ++cc) {
        const int base = cc * 32;
        ffrag s0 = {}, s1 = {};
        #pragma unroll
        for (int dc = 0; dc < 4; ++dc) {
            bfrag k0 = *(const bfrag*)(Kb + (size_t)(base + lr)      * DH + dc * 32 + lk);
            bfrag k1 = *(const bfrag*)(Kb + (size_t)(base + 16 + lr) * DH + dc * 32 + lk);
            s0 = __builtin_amdgcn_mfma_f32_16x16x32_bf16(qf[dc], k0, s0, 0, 0, 0);
            s1 = __builtin_amdgcn_mfma_f32_16x16x32_bf16(qf[dc], k1, s1, 0, 0, 0);
        }
        float p0[4], p1[4], alpha[4];
        #pragma unroll
        for (int i = 0; i < 4; ++i) {
            int row = q0 + (lane >> 4) * 4 + i;
            float v0 = (base + lr      <= row) ? s0[i] * scale : -1e30f;
            float v1 = (base + 16 + lr <= row) ? s1[i] * scale : -1e30f;
            float mx = fmaxf(v0, v1);
            #pragma unroll
            for (int off = 1; off < 16; off <<= 1) mx = fmaxf(mx, __shfl_xor(mx, off));
            float mn = fmaxf(m_i[i], mx);
            float al = __expf(m_i[i] - mn);
            float e0 = __expf(v0 - mn);
            float e1 = __expf(v1 - mn);
            float r = e0 + e1;
            #pragma unroll
            for (int off = 1; off < 16; off <<= 1) r += __shfl_xor(r, off);
            l_i[i] = l_i[i] * al + r;
            m_i[i] = mn;
            alpha[i] = al; p0[i] = e0; p1[i] = e1;
        }
        #pragma unroll
        for (int dt = 0; dt < 8; ++dt)
            #pragma unroll
            for (int i = 0; i < 4; ++i) o[dt][i] *= alpha[i];

        // P: C-layout -> A-layout via LDS
        #pragma unroll
        for (int i = 0; i < 4; ++i) {
            int r = (lane >> 4) * 4 + i;
            Pl[r * 32 + lr]      = __float2bfloat16(p0[i]);
            Pl[r * 32 + 16 + lr] = __float2bfloat16(p1[i]);
        }
        __syncthreads();
        bfrag pf = *(const bfrag*)(Pl + lr * 32 + lk);
        #pragma unroll
        for (int dt = 0; dt < 8; ++dt) {
            bfrag vf = *(const bfrag*)(Vb + (size_t)(dt * 16 + lr) * T_SEQ + base + lk);
            o[dt] = __builtin_amdgcn_mfma_f32_16x16x32_bf16(pf, vf, o[dt], 0, 0, 0);
        }
        __syncthreads();
    }

    float inv[4];
    #pragma unroll
    for (int i = 0; i < 4; ++i) inv[i] = 1.0f / l_i[i];
    #pragma unroll
    for (int dt = 0; dt < 8; ++dt)
        #pragma unroll
        for (int i = 0; i < 4; ++i) {
            int row = q0 + (lane >> 4) * 4 + i;
            int col = h * DH + dt * 16 + lr;
            Y[((size_t)(b * T_SEQ) + row) * CDIM + col] = __float2bfloat16(o[dt][i] * inv[i]);
        }
}

extern "C" void kernel_launch(void* const* d_in, const int* in_sizes, int n_in,
                              void* d_out, int out_size, void* d_ws, size_t ws_size,
                              hipStream_t stream) {
    const float* x     = (const float*)d_in[0];
    const float* Wq    = (const float*)d_in[1];
    const float* Wkv   = (const float*)d_in[2];
    const float* Wproj = (const float*)d_in[3];
    float* out = (float*)d_out;

    char* ws = (char*)d_ws;
    size_t off = 0;
    auto alloc = [&](size_t bytes) { void* p = ws + off; off += (bytes + 255) & ~255ULL; return p; };
    bf16* xb   = (bf16*)alloc((size_t)BATCH * T_SEQ * CDIM * 2);
    bf16* wqb  = (bf16*)alloc((size_t)CDIM * CDIM * 2);
    bf16* wkvb = (bf16*)alloc((size_t)2 * NKV * DH * CDIM * 2);
    bf16* wpb  = (bf16*)alloc((size_t)CDIM * CDIM * 2);
    bf16* qb   = (bf16*)alloc((size_t)BATCH * NH * T_SEQ * DH * 2);
    bf16* kb   = (bf16*)alloc((size_t)BATCH * NKV * T_SEQ * DH * 2);
    bf16* vtb  = (bf16*)alloc((size_t)BATCH * NKV * DH * T_SEQ * 2);
    bf16* y1   = (bf16*)alloc((size_t)BATCH * T_SEQ * CDIM * 2);

    int n;
    n = BATCH * T_SEQ * CDIM; cast_f2b<<<(n + 255) / 256, 256, 0, stream>>>(x, xb, n);
    n = CDIM * CDIM;          cast_f2b<<<(n + 255) / 256, 256, 0, stream>>>(Wq, wqb, n);
    n = 2 * NKV * DH * CDIM;  cast_f2b<<<(n + 255) / 256, 256, 0, stream>>>(Wkv, wkvb, n);
    n = CDIM * CDIM;          cast_f2b<<<(n + 255) / 256, 256, 0, stream>>>(Wproj, wpb, n);

    gemm_k<0><<<dim3(64, 32), 256, 0, stream>>>(xb, wqb, qb, nullptr, nullptr);
    gemm_k<1><<<dim3(64, 16), 256, 0, stream>>>(xb, wkvb, kb, vtb, nullptr);
    normrope_k<<<BATCH * NH * T_SEQ, 64, 0, stream>>>(qb, NH);
    normrope_k<<<BATCH * NKV * T_SEQ, 64, 0, stream>>>(kb, NKV);
    attn_k<<<dim3(T_SEQ / 16, NH, BATCH), 64, 0, stream>>>(qb, kb, vtb, y1);
    gemm_k<2><<<dim3(64, 32), 256, 0, stream>>>(y1, wpb, nullptr, nullptr, out);
}

// Round 2
// 721.699 us; speedup vs baseline: 1.7063x; 1.7063x over previous
//
#include <hip/hip_runtime.h>
#include <hip/hip_bf16.h>

#define T_SEQ 2048
#define BATCH 2
#define CDIM  2048
#define NH    16
#define NKV   4
#define DH    128

typedef __attribute__((ext_vector_type(8))) short bfrag;   // 8 bf16 (4 VGPRs)
typedef __attribute__((ext_vector_type(4))) float ffrag;   // 4 f32 acc
typedef __hip_bfloat16 bf16;

#if defined(__has_builtin)
#if __has_builtin(__builtin_amdgcn_global_load_lds)
#define USE_GLL 1
#endif
#endif
#ifndef USE_GLL
#define USE_GLL 0
#endif

// stage 16 B per lane: global (per-lane addr) -> LDS (wave-uniform base + lane*16)
__device__ __forceinline__ void stage16(const bf16* __restrict__ g, bf16* lds_base, int lane) {
#if USE_GLL
    __builtin_amdgcn_global_load_lds((const __attribute__((address_space(1))) void*)g,
                                     (__attribute__((address_space(3))) void*)lds_base, 16, 0, 0);
#else
    *(bfrag*)(lds_base + lane * 8) = *(const bfrag*)g;
#endif
}

// ---------------- fp32 -> bf16 cast (x4 vectorized; all sizes %4==0) ----------------
struct bf16x4 { bf16 a, b, c, d; };
__global__ void cast_f2b(const float* __restrict__ src, bf16* __restrict__ dst, int n4) {
    int i = blockIdx.x * blockDim.x + threadIdx.x;
    if (i < n4) {
        float4 f = ((const float4*)src)[i];
        bf16x4 o{__float2bfloat16(f.x), __float2bfloat16(f.y),
                 __float2bfloat16(f.z), __float2bfloat16(f.w)};
        ((bf16x4*)dst)[i] = o;
    }
}

// ---------------- GEMM: out[m][n] = sum_k A[m][k] * W[n][k] ----------------
// m97 structure: 128x128 tile, BK=32, 4 waves each computing a 64x64 quadrant.
// MODE 0: Q GEMM  -> out0 = q   (B, NH, T, DH) bf16
// MODE 1: KV GEMM -> out0 = k   (B, NKV, T, DH) bf16 ; out1 = v^T (B, NKV, DH, T) bf16
// MODE 2: proj    -> outf fp32 (B*T, C)
template<int MODE>
__global__ __launch_bounds__(256) void gemm_k(
    const bf16* __restrict__ A, const bf16* __restrict__ W,
    bf16* __restrict__ out0, bf16* __restrict__ out1, float* __restrict__ outf)
{
    __shared__ __align__(16) bf16 sA[128 * 32];
    __shared__ __align__(16) bf16 sB[128 * 32];
    const int lane = threadIdx.x & 63;
    const int w = threadIdx.x >> 6;
    const int m0 = blockIdx.x * 128, n0 = blockIdx.y * 128;
    const int lr = lane & 15, quad = lane >> 4, lk = quad * 8;
    const int m_off = (w & 1) * 64, n_off = (w >> 1) * 64;

    // staging: wave w covers rows [w*32, w*32+32) of each 128x32 tile, 2 insts of 16 rows
    const bf16* ap = A + (size_t)(m0 + w * 32 + (lane >> 2)) * CDIM + (lane & 3) * 8;
    const bf16* bp = W + (size_t)(n0 + w * 32 + (lane >> 2)) * CDIM + (lane & 3) * 8;
    bf16* sA0 = &sA[(w * 32) * 32];
    bf16* sA1 = &sA[(w * 32 + 16) * 32];
    bf16* sB0 = &sB[(w * 32) * 32];
    bf16* sB1 = &sB[(w * 32 + 16) * 32];

    ffrag acc[4][4] = {};
    for (int kk = 0; kk < CDIM; kk += 32) {
        __syncthreads();   // WAR: prior iter's ds_reads done before overwrite
        stage16(ap, sA0, lane);
        stage16(ap + (size_t)16 * CDIM, sA1, lane);
        stage16(bp, sB0, lane);
        stage16(bp + (size_t)16 * CDIM, sB1, lane);
        ap += 32; bp += 32;
        __syncthreads();   // drains vmcnt (global_load_lds) per barrier semantics

        bfrag af[4], bg[4];
        #pragma unroll
        for (int s = 0; s < 4; ++s) af[s] = *(const bfrag*)&sA[(m_off + s * 16 + lr) * 32 + lk];
        #pragma unroll
        for (int s = 0; s < 4; ++s) bg[s] = *(const bfrag*)&sB[(n_off + s * 16 + lr) * 32 + lk];
        #pragma unroll
        for (int i = 0; i < 4; ++i)
            #pragma unroll
            for (int j = 0; j < 4; ++j)
                acc[i][j] = __builtin_amdgcn_mfma_f32_16x16x32_bf16(af[i], bg[j], acc[i][j], 0, 0, 0);
    }

    #pragma unroll
    for (int si = 0; si < 4; ++si) {
        #pragma unroll
        for (int sj = 0; sj < 4; ++sj) {
            #pragma unroll
            for (int i = 0; i < 4; ++i) {
                int m = m0 + m_off + si * 16 + quad * 4 + i;
                int n = n0 + n_off + sj * 16 + lr;
                float v = acc[si][sj][i];
                if (MODE == 0) {
                    int b = m >> 11, t = m & (T_SEQ - 1);
                    int h = n >> 7, d = n & (DH - 1);
                    out0[(((size_t)(b * NH + h) * T_SEQ + t) << 7) + d] = __float2bfloat16(v);
                } else if (MODE == 1) {
                    int b = m >> 11, t = m & (T_SEQ - 1);
                    if (n < NKV * DH) {
                        int h = n >> 7, d = n & (DH - 1);
                        out0[(((size_t)(b * NKV + h) * T_SEQ + t) << 7) + d] = __float2bfloat16(v);
                    } else {
                        int n2 = n - NKV * DH;
                        int h = n2 >> 7, d = n2 & (DH - 1);
                        out1[(((size_t)(b * NKV + h) * DH + d) << 11) + t] = __float2bfloat16(v);
                    }
                } else {
                    outf[(size_t)m * CDIM + n] = v;
                }
            }
        }
    }
    if (MODE == 2 && blockIdx.x == 0 && blockIdx.y == 0 && threadIdx.x == 0) {
        outf[(size_t)BATCH * T_SEQ * CDIM] = 0.0f;   // reference's second output: 0.0
    }
}

// ---------------- RMSNorm + rotary (angle indexed by HEAD per reference) ----------------
__global__ __launch_bounds__(256) void normrope_k(bf16* __restrict__ buf, int nheads) {
    const int row = blockIdx.x * 4 + (threadIdx.x >> 6);   // (b*nheads + h)*T + t
    const int h = (row >> 11) % nheads;                    // T = 2048 = 2^11
    bf16* p = buf + (size_t)row * DH;
    const int d = threadIdx.x & 63;                        // pairs (d, d+64)
    float x1 = __bfloat162float(p[d]);
    float x2 = __bfloat162float(p[d + 64]);
    float ss = x1 * x1 + x2 * x2;
    #pragma unroll
    for (int off = 32; off; off >>= 1) ss += __shfl_xor(ss, off);
    float r = rsqrtf(ss * (1.0f / 128.0f) + 1.1920929e-07f);
    x1 *= r; x2 *= r;
    float freq = (d < 32) ? exp2f(-10.0f * (float)d * (1.0f / 31.0f)) : 0.0f;
    float th = (float)h * freq;   // head index, not position — replicates reference
    float c, s;
    __sincosf(th, &s, &c);
    p[d]      = __float2bfloat16(x1 * c + x2 * s);
    p[d + 64] = __float2bfloat16(-x1 * s + x2 * c);
}

// ---------------- Flash attention, static-max softmax ----------------
// RMS-normed q,k => |score*scale| <= sqrt(128) ~= 11.32; exp(s - 16) never overflows and
// softmax(s) == exp(s-16)/sum(exp(s-16)) exactly. No running max, no alpha rescale.
// Block: 4 waves = 4 consecutive 16-row q-tiles (rows qtb*64..+63); all waves need
// exactly nc = qtb+1 chunks of 64 keys -> uniform barriers, zero wasted chunks.
#define PSTR 72   // P row stride (bf16): 144 B = 16B-aligned rows, quad-spread banks
__global__ __launch_bounds__(256) void attn_k(const bf16* __restrict__ Q, const bf16* __restrict__ K,
                                              const bf16* __restrict__ VT, bf16* __restrict__ Y)
{
    const int lane = threadIdx.x & 63;
    const int w = threadIdx.x >> 6;
    const int qtb = blockIdx.x, h = blockIdx.y, b = blockIdx.z;
    const int q0 = qtb * 64 + w * 16;
    const int lr = lane & 15, quad = lane >> 4, lk = quad * 8;
    const bf16* Qb = Q  + (size_t)(b * NH  + h)        * T_SEQ * DH;
    const bf16* Kb = K  + (size_t)(b * NKV + (h >> 2)) * T_SEQ * DH;
    const bf16* Vb = VT + (size_t)(b * NKV + (h >> 2)) * DH * T_SEQ;

    bfrag qf[4];
    #pragma unroll
    for (int dc = 0; dc < 4; ++dc)
        qf[dc] = *(const bfrag*)(Qb + (size_t)(q0 + lr) * DH + dc * 32 + lk);

    __shared__ __align__(16) bf16 P[4][16 * PSTR];
    bf16* Pl = P[w];
    float lp[4] = {0.f, 0.f, 0.f, 0.f};
    ffrag o[8] = {};
    const float scale = 0.08838834764831845f;  // 1/sqrt(128)
    const int nc = qtb + 1;

    for (int c = 0; c < nc; ++c) {
        const int base = c * 64;
        ffrag s[4] = {};
        #pragma unroll
        for (int kt = 0; kt < 4; ++kt) {
            const bf16* kp = Kb + (size_t)(base + kt * 16 + lr) * DH + lk;
            #pragma unroll
            for (int dc = 0; dc < 4; ++dc)
                s[kt] = __builtin_amdgcn_mfma_f32_16x16x32_bf16(qf[dc], *(const bfrag*)(kp + dc * 32), s[kt], 0, 0, 0);
        }
        #pragma unroll
        for (int kt = 0; kt < 4; ++kt) {
            const int col = base + kt * 16 + lr;
            #pragma unroll
            for (int i = 0; i < 4; ++i) {
                const int row = q0 + quad * 4 + i;
                float e = (col <= row) ? __expf(fmaf(s[kt][i], scale, -16.0f)) : 0.0f;
                lp[i] += e;
                Pl[(quad * 4 + i) * PSTR + kt * 16 + lr] = __float2bfloat16(e);
            }
        }
        __syncthreads();
        const bfrag pf0 = *(const bfrag*)(Pl + lr * PSTR + lk);
        const bfrag pf1 = *(const bfrag*)(Pl + lr * PSTR + 32 + lk);
        const bf16* vp = Vb + (size_t)lr * T_SEQ + base + lk;
        #pragma unroll
        for (int dt = 0; dt < 8; ++dt) {
            o[dt] = __builtin_amdgcn_mfma_f32_16x16x32_bf16(pf0, *(const bfrag*)(vp + (size_t)dt * 16 * T_SEQ), o[dt], 0, 0, 0);
            o[dt] = __builtin_amdgcn_mfma_f32_16x16x32_bf16(pf1, *(const bfrag*)(vp + (size_t)dt * 16 * T_SEQ + 32), o[dt], 0, 0, 0);
        }
        __syncthreads();
    }

    float inv[4];
    #pragma unroll
    for (int i = 0; i < 4; ++i) {
        float l = lp[i];
        #pragma unroll
        for (int off = 1; off < 16; off <<= 1) l += __shfl_xor(l, off);
        inv[i] = 1.0f / l;
    }
    #pragma unroll
    for (int dt = 0; dt < 8; ++dt)
        #pragma unroll
        for (int i = 0; i < 4; ++i) {
            int row = q0 + quad * 4 + i;
            Y[((size_t)(b * T_SEQ) + row) * CDIM + h * DH + dt * 16 + lr] = __float2bfloat16(o[dt][i] * inv[i]);
        }
}

extern "C" void kernel_launch(void* const* d_in, const int* in_sizes, int n_in,
                              void* d_out, int out_size, void* d_ws, size_t ws_size,
                              hipStream_t stream) {
    const float* x     = (const float*)d_in[0];
    const float* Wq    = (const float*)d_in[1];
    const float* Wkv   = (const float*)d_in[2];
    const float* Wproj = (const float*)d_in[3];
    float* out = (float*)d_out;

    char* ws = (char*)d_ws;
    size_t off = 0;
    auto alloc = [&](size_t bytes) { void* p = ws + off; off += (bytes + 255) & ~255ULL; return p; };
    bf16* xb   = (bf16*)alloc((size_t)BATCH * T_SEQ * CDIM * 2);
    bf16* wqb  = (bf16*)alloc((size_t)CDIM * CDIM * 2);
    bf16* wkvb = (bf16*)alloc((size_t)2 * NKV * DH * CDIM * 2);
    bf16* wpb  = (bf16*)alloc((size_t)CDIM * CDIM * 2);
    bf16* qb   = (bf16*)alloc((size_t)BATCH * NH * T_SEQ * DH * 2);
    bf16* kb   = (bf16*)alloc((size_t)BATCH * NKV * T_SEQ * DH * 2);
    bf16* vtb  = (bf16*)alloc((size_t)BATCH * NKV * DH * T_SEQ * 2);
    bf16* y1   = (bf16*)alloc((size_t)BATCH * T_SEQ * CDIM * 2);

    int n;
    n = BATCH * T_SEQ * CDIM / 4; cast_f2b<<<(n + 255) / 256, 256, 0, stream>>>(x, xb, n);
    n = CDIM * CDIM / 4;          cast_f2b<<<(n + 255) / 256, 256, 0, stream>>>(Wq, wqb, n);
    n = 2 * NKV * DH * CDIM / 4;  cast_f2b<<<(n + 255) / 256, 256, 0, stream>>>(Wkv, wkvb, n);
    n = CDIM * CDIM / 4;          cast_f2b<<<(n + 255) / 256, 256, 0, stream>>>(Wproj, wpb, n);

    gemm_k<0><<<dim3(32, 16), 256, 0, stream>>>(xb, wqb, qb, nullptr, nullptr);
    gemm_k<1><<<dim3(32, 8),  256, 0, stream>>>(xb, wkvb, kb, vtb, nullptr);
    normrope_k<<<BATCH * NH * T_SEQ / 4,  256, 0, stream>>>(qb, NH);
    normrope_k<<<BATCH * NKV * T_SEQ / 4, 256, 0, stream>>>(kb, NKV);
    attn_k<<<dim3(T_SEQ / 64, NH, BATCH), 256, 0, stream>>>(qb, kb, vtb, y1);
    gemm_k<2><<<dim3(32, 16), 256, 0, stream>>>(y1, wpb, nullptr, nullptr, out);
}

// Round 3
// 347.917 us; speedup vs baseline: 3.5394x; 2.0743x over previous
//
#include <hip/hip_runtime.h>
#include <hip/hip_bf16.h>

#define T_SEQ 2048
#define BATCH 2
#define CDIM  2048
#define NH    16
#define NKV   4
#define DH    128

typedef __attribute__((ext_vector_type(8))) short bfrag;   // 8 bf16 (4 VGPRs)
typedef __attribute__((ext_vector_type(4))) float ffrag;   // 4 f32 acc
typedef __hip_bfloat16 bf16;

#if defined(__has_builtin)
#if __has_builtin(__builtin_amdgcn_global_load_lds)
#define USE_GLL 1
#endif
#endif
#ifndef USE_GLL
#define USE_GLL 0
#endif

__device__ __forceinline__ void stage16(const bf16* __restrict__ g, bf16* lds_base, int lane) {
#if USE_GLL
    __builtin_amdgcn_global_load_lds((const __attribute__((address_space(1))) void*)g,
                                     (__attribute__((address_space(3))) void*)lds_base, 16, 0, 0);
#else
    *(bfrag*)(lds_base + lane * 8) = *(const bfrag*)g;
#endif
}

// ---------------- fp32 -> bf16 cast (x4 vectorized; all sizes %4==0) ----------------
struct bf16x4 { bf16 a, b, c, d; };
__global__ void cast_f2b(const float* __restrict__ src, bf16* __restrict__ dst, int n4) {
    int i = blockIdx.x * blockDim.x + threadIdx.x;
    if (i < n4) {
        float4 f = ((const float4*)src)[i];
        bf16x4 o{__float2bfloat16(f.x), __float2bfloat16(f.y),
                 __float2bfloat16(f.z), __float2bfloat16(f.w)};
        ((bf16x4*)dst)[i] = o;
    }
}

// ---------------- GEMM (m97 structure, unchanged from R2) ----------------
template<int MODE>
__global__ __launch_bounds__(256) void gemm_k(
    const bf16* __restrict__ A, const bf16* __restrict__ W,
    bf16* __restrict__ out0, bf16* __restrict__ out1, float* __restrict__ outf)
{
    __shared__ __align__(16) bf16 sA[128 * 32];
    __shared__ __align__(16) bf16 sB[128 * 32];
    const int lane = threadIdx.x & 63;
    const int w = threadIdx.x >> 6;
    const int m0 = blockIdx.x * 128, n0 = blockIdx.y * 128;
    const int lr = lane & 15, quad = lane >> 4, lk = quad * 8;
    const int m_off = (w & 1) * 64, n_off = (w >> 1) * 64;

    const bf16* ap = A + (size_t)(m0 + w * 32 + (lane >> 2)) * CDIM + (lane & 3) * 8;
    const bf16* bp = W + (size_t)(n0 + w * 32 + (lane >> 2)) * CDIM + (lane & 3) * 8;
    bf16* sA0 = &sA[(w * 32) * 32];
    bf16* sA1 = &sA[(w * 32 + 16) * 32];
    bf16* sB0 = &sB[(w * 32) * 32];
    bf16* sB1 = &sB[(w * 32 + 16) * 32];

    ffrag acc[4][4] = {};
    for (int kk = 0; kk < CDIM; kk += 32) {
        __syncthreads();
        stage16(ap, sA0, lane);
        stage16(ap + (size_t)16 * CDIM, sA1, lane);
        stage16(bp, sB0, lane);
        stage16(bp + (size_t)16 * CDIM, sB1, lane);
        ap += 32; bp += 32;
        __syncthreads();

        bfrag af[4], bg[4];
        #pragma unroll
        for (int s = 0; s < 4; ++s) af[s] = *(const bfrag*)&sA[(m_off + s * 16 + lr) * 32 + lk];
        #pragma unroll
        for (int s = 0; s < 4; ++s) bg[s] = *(const bfrag*)&sB[(n_off + s * 16 + lr) * 32 + lk];
        #pragma unroll
        for (int i = 0; i < 4; ++i)
            #pragma unroll
            for (int j = 0; j < 4; ++j)
                acc[i][j] = __builtin_amdgcn_mfma_f32_16x16x32_bf16(af[i], bg[j], acc[i][j], 0, 0, 0);
    }

    #pragma unroll
    for (int si = 0; si < 4; ++si) {
        #pragma unroll
        for (int sj = 0; sj < 4; ++sj) {
            #pragma unroll
            for (int i = 0; i < 4; ++i) {
                int m = m0 + m_off + si * 16 + quad * 4 + i;
                int n = n0 + n_off + sj * 16 + lr;
                float v = acc[si][sj][i];
                if (MODE == 0) {
                    int b = m >> 11, t = m & (T_SEQ - 1);
                    int h = n >> 7, d = n & (DH - 1);
                    out0[(((size_t)(b * NH + h) * T_SEQ + t) << 7) + d] = __float2bfloat16(v);
                } else if (MODE == 1) {
                    int b = m >> 11, t = m & (T_SEQ - 1);
                    if (n < NKV * DH) {
                        int h = n >> 7, d = n & (DH - 1);
                        out0[(((size_t)(b * NKV + h) * T_SEQ + t) << 7) + d] = __float2bfloat16(v);
                    } else {
                        int n2 = n - NKV * DH;
                        int h = n2 >> 7, d = n2 & (DH - 1);
                        out1[(((size_t)(b * NKV + h) * DH + d) << 11) + t] = __float2bfloat16(v);
                    }
                } else {
                    outf[(size_t)m * CDIM + n] = v;
                }
            }
        }
    }
    if (MODE == 2 && blockIdx.x == 0 && blockIdx.y == 0 && threadIdx.x == 0) {
        outf[(size_t)BATCH * T_SEQ * CDIM] = 0.0f;
    }
}

// ---------------- RMSNorm + rotary (angle indexed by HEAD per reference) ----------------
__global__ __launch_bounds__(256) void normrope_k(bf16* __restrict__ buf, int nheads) {
    const int row = blockIdx.x * 4 + (threadIdx.x >> 6);
    const int h = (row >> 11) % nheads;
    bf16* p = buf + (size_t)row * DH;
    const int d = threadIdx.x & 63;
    float x1 = __bfloat162float(p[d]);
    float x2 = __bfloat162float(p[d + 64]);
    float ss = x1 * x1 + x2 * x2;
    #pragma unroll
    for (int off = 32; off; off >>= 1) ss += __shfl_xor(ss, off);
    float r = rsqrtf(ss * (1.0f / 128.0f) + 1.1920929e-07f);
    x1 *= r; x2 *= r;
    float freq = (d < 32) ? exp2f(-10.0f * (float)d * (1.0f / 31.0f)) : 0.0f;
    float th = (float)h * freq;
    float c, s;
    __sincosf(th, &s, &c);
    p[d]      = __float2bfloat16(x1 * c + x2 * s);
    p[d + 64] = __float2bfloat16(-x1 * s + x2 * c);
}

// ---------------- Flash attention v3: LDS-staged K/V, balanced pairs ----------------
// Static-max softmax (RMS-normed q,k => |score*scale| <= 11.32; exp(s-16) exact softmax).
// Block = 4 waves; handles q-blocks {p, 31-p} sequentially => uniform 33 chunks/block.
// Per 64-key chunk: K(16KB)+V(16KB) staged to LDS cooperatively (coalesced), VGPR
// prefetch one chunk ahead stays in flight across barriers (plain loads, no vmcnt drain).
// LDS strides: SK row 136 elts (272B), SV row 72 elts (144B), SP row 72 — all 16B-aligned,
// dword-stride = 4 mod 32 => each b128 16-lane phase hits every bank exactly 2x (free).
#define PSTR 72
#define KSTR 136
#define VSTR 72
__global__ __launch_bounds__(256) void attn_k(const bf16* __restrict__ Q, const bf16* __restrict__ K,
                                              const bf16* __restrict__ VT, bf16* __restrict__ Y)
{
    const int lane = threadIdx.x & 63;
    const int w = threadIdx.x >> 6;
    const int p = blockIdx.x, h = blockIdx.y, b = blockIdx.z;
    const int lr = lane & 15, quad = lane >> 4, lk = quad * 8;
    const bf16* Qb = Q  + (size_t)(b * NH  + h)        * T_SEQ * DH;
    const bf16* Kb = K  + (size_t)(b * NKV + (h >> 2)) * T_SEQ * DH;
    const bf16* Vb = VT + (size_t)(b * NKV + (h >> 2)) * DH * T_SEQ;

    __shared__ __align__(16) bf16 SK[64 * KSTR];
    __shared__ __align__(16) bf16 SV[128 * VSTR];
    __shared__ __align__(16) bf16 SP[4][16 * PSTR];
    bf16* Pl = SP[w];

    // staging coordinates (wave w covers K rows w*16..+15 per j, V rows w*32..+31)
    const int krow = w * 16 + (lane >> 4);      // + j*4
    const int kcol = (lane & 15) * 8;
    const int vrow = w * 32 + (lane >> 3);      // + j*8
    const int vcol = (lane & 7) * 8;
    const float scale = 0.08838834764831845f;   // 1/sqrt(128)

    for (int pass = 0; pass < 2; ++pass) {
        const int qblk = pass ? (31 - p) : p;
        const int nc = qblk + 1;
        const int q0 = qblk * 64 + w * 16;

        bfrag qf[4];
        #pragma unroll
        for (int dc = 0; dc < 4; ++dc)
            qf[dc] = *(const bfrag*)(Qb + (size_t)(q0 + lr) * DH + dc * 32 + lk);

        float lp[4] = {0.f, 0.f, 0.f, 0.f};
        ffrag o[8] = {};

        // prefetch chunk 0
        bfrag kr[4], vr[4];
        #pragma unroll
        for (int j = 0; j < 4; ++j) {
            kr[j] = *(const bfrag*)(Kb + (size_t)(krow + j * 4) * DH + kcol);
            vr[j] = *(const bfrag*)(Vb + (size_t)(vrow + j * 8) * T_SEQ + vcol);
        }

        for (int c = 0; c < nc; ++c) {
            const int base = c * 64;
            __syncthreads();   // all waves done reading SK/SV from previous chunk/pass
            #pragma unroll
            for (int j = 0; j < 4; ++j) {
                *(bfrag*)&SK[(size_t)(w * 16 + j * 4 + (lane >> 4)) * KSTR + kcol] = kr[j];
                *(bfrag*)&SV[(size_t)(w * 32 + j * 8 + (lane >> 3)) * VSTR + vcol] = vr[j];
            }
            if (c + 1 < nc) {   // prefetch next chunk; loads stay in flight across barrier
                const int nb = base + 64;
                #pragma unroll
                for (int j = 0; j < 4; ++j) {
                    kr[j] = *(const bfrag*)(Kb + (size_t)(nb + krow + j * 4) * DH + kcol);
                    vr[j] = *(const bfrag*)(Vb + (size_t)(vrow + j * 8) * T_SEQ + nb + vcol);
                }
            }
            __syncthreads();   // staged data visible

            // QK^T from LDS
            ffrag s[4] = {};
            #pragma unroll
            for (int kt = 0; kt < 4; ++kt) {
                const bf16* kp = &SK[(kt * 16 + lr) * KSTR + lk];
                #pragma unroll
                for (int dc = 0; dc < 4; ++dc)
                    s[kt] = __builtin_amdgcn_mfma_f32_16x16x32_bf16(qf[dc], *(const bfrag*)(kp + dc * 32), s[kt], 0, 0, 0);
            }

            // softmax numerator (static max), P -> LDS (C-layout -> A-layout)
            if (c == qblk) {   // only the diagonal chunk needs masking (wave-uniform branch)
                #pragma unroll
                for (int kt = 0; kt < 4; ++kt) {
                    const int col = base + kt * 16 + lr;
                    #pragma unroll
                    for (int i = 0; i < 4; ++i) {
                        const int row = q0 + quad * 4 + i;
                        float e = (col <= row) ? __expf(fmaf(s[kt][i], scale, -16.0f)) : 0.0f;
                        lp[i] += e;
                        Pl[(quad * 4 + i) * PSTR + kt * 16 + lr] = __float2bfloat16(e);
                    }
                }
            } else {
                #pragma unroll
                for (int kt = 0; kt < 4; ++kt) {
                    #pragma unroll
                    for (int i = 0; i < 4; ++i) {
                        float e = __expf(fmaf(s[kt][i], scale, -16.0f));
                        lp[i] += e;
                        Pl[(quad * 4 + i) * PSTR + kt * 16 + lr] = __float2bfloat16(e);
                    }
                }
            }

            // P.V from LDS (per-wave P buffer: no barrier needed, lgkmcnt handles RAW)
            const bfrag pf0 = *(const bfrag*)&Pl[lr * PSTR + lk];
            const bfrag pf1 = *(const bfrag*)&Pl[lr * PSTR + 32 + lk];
            #pragma unroll
            for (int dt = 0; dt < 8; ++dt) {
                const bf16* vp = &SV[(dt * 16 + lr) * VSTR + lk];
                o[dt] = __builtin_amdgcn_mfma_f32_16x16x32_bf16(pf0, *(const bfrag*)vp, o[dt], 0, 0, 0);
                o[dt] = __builtin_amdgcn_mfma_f32_16x16x32_bf16(pf1, *(const bfrag*)(vp + 32), o[dt], 0, 0, 0);
            }
        }

        float inv[4];
        #pragma unroll
        for (int i = 0; i < 4; ++i) {
            float l = lp[i];
            #pragma unroll
            for (int off = 1; off < 16; off <<= 1) l += __shfl_xor(l, off);
            inv[i] = 1.0f / l;
        }
        #pragma unroll
        for (int dt = 0; dt < 8; ++dt)
            #pragma unroll
            for (int i = 0; i < 4; ++i) {
                int row = q0 + quad * 4 + i;
                Y[((size_t)(b * T_SEQ) + row) * CDIM + h * DH + dt * 16 + lr] = __float2bfloat16(o[dt][i] * inv[i]);
            }
    }
}

extern "C" void kernel_launch(void* const* d_in, const int* in_sizes, int n_in,
                              void* d_out, int out_size, void* d_ws, size_t ws_size,
                              hipStream_t stream) {
    const float* x     = (const float*)d_in[0];
    const float* Wq    = (const float*)d_in[1];
    const float* Wkv   = (const float*)d_in[2];
    const float* Wproj = (const float*)d_in[3];
    float* out = (float*)d_out;

    char* ws = (char*)d_ws;
    size_t off = 0;
    auto alloc = [&](size_t bytes) { void* p = ws + off; off += (bytes + 255) & ~255ULL; return p; };
    bf16* xb   = (bf16*)alloc((size_t)BATCH * T_SEQ * CDIM * 2);
    bf16* wqb  = (bf16*)alloc((size_t)CDIM * CDIM * 2);
    bf16* wkvb = (bf16*)alloc((size_t)2 * NKV * DH * CDIM * 2);
    bf16* wpb  = (bf16*)alloc((size_t)CDIM * CDIM * 2);
    bf16* qb   = (bf16*)alloc((size_t)BATCH * NH * T_SEQ * DH * 2);
    bf16* kb   = (bf16*)alloc((size_t)BATCH * NKV * T_SEQ * DH * 2);
    bf16* vtb  = (bf16*)alloc((size_t)BATCH * NKV * DH * T_SEQ * 2);
    bf16* y1   = (bf16*)alloc((size_t)BATCH * T_SEQ * CDIM * 2);

    int n;
    n = BATCH * T_SEQ * CDIM / 4; cast_f2b<<<(n + 255) / 256, 256, 0, stream>>>(x, xb, n);
    n = CDIM * CDIM / 4;          cast_f2b<<<(n + 255) / 256, 256, 0, stream>>>(Wq, wqb, n);
    n = 2 * NKV * DH * CDIM / 4;  cast_f2b<<<(n + 255) / 256, 256, 0, stream>>>(Wkv, wkvb, n);
    n = CDIM * CDIM / 4;          cast_f2b<<<(n + 255) / 256, 256, 0, stream>>>(Wproj, wpb, n);

    gemm_k<0><<<dim3(32, 16), 256, 0, stream>>>(xb, wqb, qb, nullptr, nullptr);
    gemm_k<1><<<dim3(32, 8),  256, 0, stream>>>(xb, wkvb, kb, vtb, nullptr);
    normrope_k<<<BATCH * NH * T_SEQ / 4,  256, 0, stream>>>(qb, NH);
    normrope_k<<<BATCH * NKV * T_SEQ / 4, 256, 0, stream>>>(kb, NKV);
    attn_k<<<dim3(16, NH, BATCH), 256, 0, stream>>>(qb, kb, vtb, y1);
    gemm_k<2><<<dim3(32, 16), 256, 0, stream>>>(y1, wpb, nullptr, nullptr, out);
}

// Round 4
// 314.257 us; speedup vs baseline: 3.9184x; 1.1071x over previous
//
#include <hip/hip_runtime.h>
#include <hip/hip_bf16.h>

#define T_SEQ 2048
#define BATCH 2
#define CDIM  2048
#define NH    16
#define NKV   4
#define DH    128

typedef __attribute__((ext_vector_type(8))) short bfrag;   // 8 bf16 (4 VGPRs)
typedef __attribute__((ext_vector_type(4))) float ffrag;   // 4 f32 acc
typedef __hip_bfloat16 bf16;

#if defined(__has_builtin)
#if __has_builtin(__builtin_amdgcn_global_load_lds)
#define USE_GLL 1
#endif
#endif
#ifndef USE_GLL
#define USE_GLL 0
#endif

__device__ __forceinline__ void stage16(const bf16* __restrict__ g, bf16* lds_base, int lane) {
#if USE_GLL
    __builtin_amdgcn_global_load_lds((const __attribute__((address_space(1))) void*)g,
                                     (__attribute__((address_space(3))) void*)lds_base, 16, 0, 0);
#else
    *(bfrag*)(lds_base + lane * 8) = *(const bfrag*)g;
#endif
}

// ---------------- merged fp32 -> bf16 cast of all 4 inputs ----------------
struct bf16x4 { bf16 a, b, c, d; };
#define N4_X   (BATCH * T_SEQ * CDIM / 4)
#define N4_WQ  (CDIM * CDIM / 4)
#define N4_WKV (2 * NKV * DH * CDIM / 4)
#define N4_WP  (CDIM * CDIM / 4)
__global__ __launch_bounds__(256) void cast_all(
    const float* __restrict__ x, const float* __restrict__ wq,
    const float* __restrict__ wkv, const float* __restrict__ wp,
    bf16* __restrict__ xb, bf16* __restrict__ wqb, bf16* __restrict__ wkvb, bf16* __restrict__ wpb)
{
    int j = blockIdx.x * 256 + threadIdx.x;
    const float* s; bf16* d;
    if (j < N4_X) { s = x; d = xb; }
    else {
        j -= N4_X;
        if (j < N4_WQ) { s = wq; d = wqb; }
        else {
            j -= N4_WQ;
            if (j < N4_WKV) { s = wkv; d = wkvb; }
            else { j -= N4_WKV; if (j >= N4_WP) return; s = wp; d = wpb; }
        }
    }
    float4 f = ((const float4*)s)[j];
    bf16x4 o{__float2bfloat16(f.x), __float2bfloat16(f.y),
             __float2bfloat16(f.z), __float2bfloat16(f.w)};
    ((bf16x4*)d)[j] = o;
}

// ---------------- GEMM body (m97 structure) ----------------
// MODE 0: Q -> (B,NH,T,DH) bf16 ; MODE 1: KV -> k (B,NKV,T,DH) + v^T (B,NKV,DH,T)
// MODE 2: proj -> fp32 (B*T, C)
template<int MODE>
__device__ __forceinline__ void gemm_body(
    const bf16* __restrict__ A, const bf16* __restrict__ W, int m0, int n0,
    bf16* __restrict__ out0, bf16* __restrict__ out1, float* __restrict__ outf)
{
    __shared__ __align__(16) bf16 sA[128 * 32];
    __shared__ __align__(16) bf16 sB[128 * 32];
    const int lane = threadIdx.x & 63;
    const int w = threadIdx.x >> 6;
    const int lr = lane & 15, quad = lane >> 4, lk = quad * 8;
    const int m_off = (w & 1) * 64, n_off = (w >> 1) * 64;

    const bf16* ap = A + (size_t)(m0 + w * 32 + (lane >> 2)) * CDIM + (lane & 3) * 8;
    const bf16* bp = W + (size_t)(n0 + w * 32 + (lane >> 2)) * CDIM + (lane & 3) * 8;
    bf16* sA0 = &sA[(w * 32) * 32];
    bf16* sA1 = &sA[(w * 32 + 16) * 32];
    bf16* sB0 = &sB[(w * 32) * 32];
    bf16* sB1 = &sB[(w * 32 + 16) * 32];

    ffrag acc[4][4] = {};
    for (int kk = 0; kk < CDIM; kk += 32) {
        __syncthreads();
        stage16(ap, sA0, lane);
        stage16(ap + (size_t)16 * CDIM, sA1, lane);
        stage16(bp, sB0, lane);
        stage16(bp + (size_t)16 * CDIM, sB1, lane);
        ap += 32; bp += 32;
        __syncthreads();

        bfrag af[4], bg[4];
        #pragma unroll
        for (int s = 0; s < 4; ++s) af[s] = *(const bfrag*)&sA[(m_off + s * 16 + lr) * 32 + lk];
        #pragma unroll
        for (int s = 0; s < 4; ++s) bg[s] = *(const bfrag*)&sB[(n_off + s * 16 + lr) * 32 + lk];
        #pragma unroll
        for (int i = 0; i < 4; ++i)
            #pragma unroll
            for (int j = 0; j < 4; ++j)
                acc[i][j] = __builtin_amdgcn_mfma_f32_16x16x32_bf16(af[i], bg[j], acc[i][j], 0, 0, 0);
    }

    #pragma unroll
    for (int si = 0; si < 4; ++si) {
        #pragma unroll
        for (int sj = 0; sj < 4; ++sj) {
            #pragma unroll
            for (int i = 0; i < 4; ++i) {
                int m = m0 + m_off + si * 16 + quad * 4 + i;
                int n = n0 + n_off + sj * 16 + lr;
                float v = acc[si][sj][i];
                if (MODE == 0) {
                    int b = m >> 11, t = m & (T_SEQ - 1);
                    int h = n >> 7, d = n & (DH - 1);
                    out0[(((size_t)(b * NH + h) * T_SEQ + t) << 7) + d] = __float2bfloat16(v);
                } else if (MODE == 1) {
                    int b = m >> 11, t = m & (T_SEQ - 1);
                    if (n < NKV * DH) {
                        int h = n >> 7, d = n & (DH - 1);
                        out0[(((size_t)(b * NKV + h) * T_SEQ + t) << 7) + d] = __float2bfloat16(v);
                    } else {
                        int n2 = n - NKV * DH;
                        int h = n2 >> 7, d = n2 & (DH - 1);
                        out1[(((size_t)(b * NKV + h) * DH + d) << 11) + t] = __float2bfloat16(v);
                    }
                } else {
                    outf[(size_t)m * CDIM + n] = v;
                }
            }
        }
    }
}

// Q (y<16) and KV (y>=16) fused in one launch: 768 blocks = 3/CU
__global__ __launch_bounds__(256) void gemm_qkv(
    const bf16* __restrict__ A, const bf16* __restrict__ Wq, const bf16* __restrict__ Wkv,
    bf16* __restrict__ q, bf16* __restrict__ k, bf16* __restrict__ vt)
{
    if (blockIdx.y < 16)
        gemm_body<0>(A, Wq, blockIdx.x * 128, blockIdx.y * 128, q, nullptr, nullptr);
    else
        gemm_body<1>(A, Wkv, blockIdx.x * 128, (blockIdx.y - 16) * 128, k, vt, nullptr);
}

__global__ __launch_bounds__(256) void gemm_proj(
    const bf16* __restrict__ A, const bf16* __restrict__ W, float* __restrict__ outf)
{
    gemm_body<2>(A, W, blockIdx.x * 128, blockIdx.y * 128, nullptr, nullptr, outf);
    if (blockIdx.x == 0 && blockIdx.y == 0 && threadIdx.x == 0)
        outf[(size_t)BATCH * T_SEQ * CDIM] = 0.0f;   // reference's second output: 0.0
}

// ---------------- RMSNorm + rotary (angle indexed by HEAD per reference) ----------------
__global__ __launch_bounds__(256) void normrope_k(bf16* __restrict__ buf, int nheads) {
    const int row = blockIdx.x * 4 + (threadIdx.x >> 6);
    const int h = (row >> 11) % nheads;
    bf16* p = buf + (size_t)row * DH;
    const int d = threadIdx.x & 63;
    float x1 = __bfloat162float(p[d]);
    float x2 = __bfloat162float(p[d + 64]);
    float ss = x1 * x1 + x2 * x2;
    #pragma unroll
    for (int off = 32; off; off >>= 1) ss += __shfl_xor(ss, off);
    float r = rsqrtf(ss * (1.0f / 128.0f) + 1.1920929e-07f);
    x1 *= r; x2 *= r;
    float freq = (d < 32) ? exp2f(-10.0f * (float)d * (1.0f / 31.0f)) : 0.0f;
    float th = (float)h * freq;
    float c, s;
    __sincosf(th, &s, &c);
    p[d]      = __float2bfloat16(x1 * c + x2 * s);
    p[d + 64] = __float2bfloat16(-x1 * s + x2 * c);
}

// ---------------- Flash attention v4: 32 q-rows/wave, swizzled P ----------------
// Static-max softmax (RMS-normed q,k => |score*scale| <= 11.32; exp(s-16) is exact softmax).
// Block = 4 waves x 32 rows = 128-row q-block; pairs (p, 15-p) => uniform 34 chunks of 64
// keys. K/V staged to LDS once per chunk; each B-frag read feeds TWO row-tiles (64 MFMA per
// 36 ds_read_b128). P stored with 4x4-transposed row index so the 4 quads of a b16-store
// land 4 banks apart (<=2-way = free); fragment reads stay bank-uniform.
#define PSTR 72
#define KSTR 136
#define VSTR 72
__global__ __launch_bounds__(256) void attn_k(const bf16* __restrict__ Q, const bf16* __restrict__ K,
                                              const bf16* __restrict__ VT, bf16* __restrict__ Y)
{
    const int lane = threadIdx.x & 63;
    const int w = threadIdx.x >> 6;
    const int p = blockIdx.x, h = blockIdx.y, b = blockIdx.z;
    const int lr = lane & 15, quad = lane >> 4, lk = quad * 8;
    const bf16* Qb = Q  + (size_t)(b * NH  + h)        * T_SEQ * DH;
    const bf16* Kb = K  + (size_t)(b * NKV + (h >> 2)) * T_SEQ * DH;
    const bf16* Vb = VT + (size_t)(b * NKV + (h >> 2)) * DH * T_SEQ;

    __shared__ __align__(16) bf16 SK[64 * KSTR];
    __shared__ __align__(16) bf16 SV[128 * VSTR];
    __shared__ __align__(16) bf16 SP[4][2][16 * PSTR];

    const int krow = w * 16 + (lane >> 4);      // + j*4
    const int kcol = (lane & 15) * 8;
    const int vrow = w * 32 + (lane >> 3);      // + j*8
    const int vcol = (lane & 7) * 8;
    const int prow = ((lr & 3) << 2) | (lr >> 2);   // P read row (matches write swizzle)
    const float scale = 0.08838834764831845f;   // 1/sqrt(128)

    for (int pass = 0; pass < 2; ++pass) {
        const int qb = pass ? (15 - p) : p;
        const int nc = 2 * (qb + 1);
        const int q0 = qb * 128 + w * 32;       // wave rows q0..q0+31 (two 16-row tiles)

        bfrag qf[2][4];
        #pragma unroll
        for (int t = 0; t < 2; ++t)
            #pragma unroll
            for (int dc = 0; dc < 4; ++dc)
                qf[t][dc] = *(const bfrag*)(Qb + (size_t)(q0 + t * 16 + lr) * DH + dc * 32 + lk);

        float lp[2][4] = {};
        ffrag o[2][8] = {};

        bfrag kr[4], vr[4];   // prefetch chunk 0
        #pragma unroll
        for (int j = 0; j < 4; ++j) {
            kr[j] = *(const bfrag*)(Kb + (size_t)(krow + j * 4) * DH + kcol);
            vr[j] = *(const bfrag*)(Vb + (size_t)(vrow + j * 8) * T_SEQ + vcol);
        }

        for (int c = 0; c < nc; ++c) {
            const int base = c * 64;
            __syncthreads();   // all waves done reading SK/SV from previous chunk
            #pragma unroll
            for (int j = 0; j < 4; ++j) {
                *(bfrag*)&SK[(size_t)(krow + j * 4) * KSTR + kcol] = kr[j];
                *(bfrag*)&SV[(size_t)(vrow + j * 8) * VSTR + vcol] = vr[j];
            }
            if (c + 1 < nc) {   // prefetch next chunk; stays in flight across barrier
                const int nb = base + 64;
                #pragma unroll
                for (int j = 0; j < 4; ++j) {
                    kr[j] = *(const bfrag*)(Kb + (size_t)(nb + krow + j * 4) * DH + kcol);
                    vr[j] = *(const bfrag*)(Vb + (size_t)(vrow + j * 8) * T_SEQ + nb + vcol);
                }
            }
            __syncthreads();   // staged data visible

            // QK^T: one K-frag read feeds both row-tiles
            ffrag s[2][4] = {};
            #pragma unroll
            for (int kt = 0; kt < 4; ++kt) {
                const bf16* kp = &SK[(kt * 16 + lr) * KSTR + lk];
                #pragma unroll
                for (int dc = 0; dc < 4; ++dc) {
                    bfrag kf = *(const bfrag*)(kp + dc * 32);
                    s[0][kt] = __builtin_amdgcn_mfma_f32_16x16x32_bf16(qf[0][dc], kf, s[0][kt], 0, 0, 0);
                    s[1][kt] = __builtin_amdgcn_mfma_f32_16x16x32_bf16(qf[1][dc], kf, s[1][kt], 0, 0, 0);
                }
            }

            // softmax numerator (static max); P -> LDS with swizzled row (i*4+quad)
            const bool maskc = (c >= 2 * qb);   // only last two chunks touch the diagonal
            #pragma unroll
            for (int t = 0; t < 2; ++t) {
                bf16* Pl = SP[w][t];
                #pragma unroll
                for (int kt = 0; kt < 4; ++kt) {
                    const int col = base + kt * 16 + lr;
                    #pragma unroll
                    for (int i = 0; i < 4; ++i) {
                        const int row = q0 + t * 16 + quad * 4 + i;
                        float e = (!maskc || col <= row) ? __expf(fmaf(s[t][kt][i], scale, -16.0f)) : 0.0f;
                        lp[t][i] += e;
                        Pl[(i * 4 + quad) * PSTR + kt * 16 + lr] = __float2bfloat16(e);
                    }
                }
            }

            // P.V: one V-frag read feeds both row-tiles (per-wave P: lgkmcnt handles RAW)
            bfrag pf[2][2];
            #pragma unroll
            for (int t = 0; t < 2; ++t) {
                pf[t][0] = *(const bfrag*)&SP[w][t][prow * PSTR + lk];
                pf[t][1] = *(const bfrag*)&SP[w][t][prow * PSTR + 32 + lk];
            }
            #pragma unroll
            for (int dt = 0; dt < 8; ++dt) {
                const bf16* vp = &SV[(dt * 16 + lr) * VSTR + lk];
                bfrag vf0 = *(const bfrag*)vp;
                bfrag vf1 = *(const bfrag*)(vp + 32);
                #pragma unroll
                for (int t = 0; t < 2; ++t) {
                    o[t][dt] = __builtin_amdgcn_mfma_f32_16x16x32_bf16(pf[t][0], vf0, o[t][dt], 0, 0, 0);
                    o[t][dt] = __builtin_amdgcn_mfma_f32_16x16x32_bf16(pf[t][1], vf1, o[t][dt], 0, 0, 0);
                }
            }
        }

        #pragma unroll
        for (int t = 0; t < 2; ++t) {
            float inv[4];
            #pragma unroll
            for (int i = 0; i < 4; ++i) {
                float l = lp[t][i];
                #pragma unroll
                for (int off = 1; off < 16; off <<= 1) l += __shfl_xor(l, off);
                inv[i] = 1.0f / l;
            }
            #pragma unroll
            for (int dt = 0; dt < 8; ++dt)
                #pragma unroll
                for (int i = 0; i < 4; ++i) {
                    int row = q0 + t * 16 + quad * 4 + i;
                    Y[((size_t)(b * T_SEQ) + row) * CDIM + h * DH + dt * 16 + lr] =
                        __float2bfloat16(o[t][dt][i] * inv[i]);
                }
        }
    }
}

extern "C" void kernel_launch(void* const* d_in, const int* in_sizes, int n_in,
                              void* d_out, int out_size, void* d_ws, size_t ws_size,
                              hipStream_t stream) {
    const float* x     = (const float*)d_in[0];
    const float* Wq    = (const float*)d_in[1];
    const float* Wkv   = (const float*)d_in[2];
    const float* Wproj = (const float*)d_in[3];
    float* out = (float*)d_out;

    char* ws = (char*)d_ws;
    size_t off = 0;
    auto alloc = [&](size_t bytes) { void* p = ws + off; off += (bytes + 255) & ~255ULL; return p; };
    bf16* xb   = (bf16*)alloc((size_t)BATCH * T_SEQ * CDIM * 2);
    bf16* wqb  = (bf16*)alloc((size_t)CDIM * CDIM * 2);
    bf16* wkvb = (bf16*)alloc((size_t)2 * NKV * DH * CDIM * 2);
    bf16* wpb  = (bf16*)alloc((size_t)CDIM * CDIM * 2);
    bf16* qb   = (bf16*)alloc((size_t)BATCH * NH * T_SEQ * DH * 2);
    bf16* kb   = (bf16*)alloc((size_t)BATCH * NKV * T_SEQ * DH * 2);
    bf16* vtb  = (bf16*)alloc((size_t)BATCH * NKV * DH * T_SEQ * 2);
    bf16* y1   = (bf16*)alloc((size_t)BATCH * T_SEQ * CDIM * 2);

    const int total4 = N4_X + N4_WQ + N4_WKV + N4_WP;
    cast_all<<<(total4 + 255) / 256, 256, 0, stream>>>(x, Wq, Wkv, Wproj, xb, wqb, wkvb, wpb);

    gemm_qkv<<<dim3(32, 24), 256, 0, stream>>>(xb, wqb, wkvb, qb, kb, vtb);
    normrope_k<<<BATCH * NH * T_SEQ / 4,  256, 0, stream>>>(qb, NH);
    normrope_k<<<BATCH * NKV * T_SEQ / 4, 256, 0, stream>>>(kb, NKV);
    attn_k<<<dim3(8, NH, BATCH), 256, 0, stream>>>(qb, kb, vtb, y1);
    gemm_proj<<<dim3(32, 16), 256, 0, stream>>>(y1, wpb, out);
}

// Round 5
// 302.110 us; speedup vs baseline: 4.0760x; 1.0402x over previous
//
#include <hip/hip_runtime.h>
#include <hip/hip_bf16.h>

#define T_SEQ 2048
#define BATCH 2
#define CDIM  2048
#define NH    16
#define NKV   4
#define DH    128

typedef __attribute__((ext_vector_type(8))) short bfrag;   // 8 bf16 (4 VGPRs)
typedef __attribute__((ext_vector_type(4))) float ffrag;   // 4 f32 acc
typedef __hip_bfloat16 bf16;

#if defined(__has_builtin)
#if __has_builtin(__builtin_amdgcn_global_load_lds)
#define USE_GLL 1
#endif
#endif
#ifndef USE_GLL
#define USE_GLL 0
#endif

__device__ __forceinline__ void stage16(const bf16* __restrict__ g, bf16* lds_base, int lane) {
#if USE_GLL
    __builtin_amdgcn_global_load_lds((const __attribute__((address_space(1))) void*)g,
                                     (__attribute__((address_space(3))) void*)lds_base, 16, 0, 0);
#else
    *(bfrag*)(lds_base + lane * 8) = *(const bfrag*)g;
#endif
}

// ---------------- merged fp32 -> bf16 cast of all 4 inputs ----------------
struct bf16x4 { bf16 a, b, c, d; };
#define N4_X   (BATCH * T_SEQ * CDIM / 4)
#define N4_WQ  (CDIM * CDIM / 4)
#define N4_WKV (2 * NKV * DH * CDIM / 4)
#define N4_WP  (CDIM * CDIM / 4)
__global__ __launch_bounds__(256) void cast_all(
    const float* __restrict__ x, const float* __restrict__ wq,
    const float* __restrict__ wkv, const float* __restrict__ wp,
    bf16* __restrict__ xb, bf16* __restrict__ wqb, bf16* __restrict__ wkvb, bf16* __restrict__ wpb)
{
    int j = blockIdx.x * 256 + threadIdx.x;
    const float* s; bf16* d;
    if (j < N4_X) { s = x; d = xb; }
    else {
        j -= N4_X;
        if (j < N4_WQ) { s = wq; d = wqb; }
        else {
            j -= N4_WQ;
            if (j < N4_WKV) { s = wkv; d = wkvb; }
            else { j -= N4_WKV; if (j >= N4_WP) return; s = wp; d = wpb; }
        }
    }
    float4 f = ((const float4*)s)[j];
    bf16x4 o{__float2bfloat16(f.x), __float2bfloat16(f.y),
             __float2bfloat16(f.z), __float2bfloat16(f.w)};
    ((bf16x4*)d)[j] = o;
}

// ---------------- GEMM body (m97 structure + XOR-chunk LDS swizzle) ----------------
// LDS rows are 32 elts = 4 chunks of 8; chunk c of row r stored at c ^ sw(r),
// sw(r) = (r + r/4) & 3 (r = row mod 16). Makes fragment ds_read_b128 2-way (free)
// instead of 8-way, without padding (global_load_lds needs contiguous rows).
template<int MODE>
__device__ __forceinline__ void gemm_body(
    const bf16* __restrict__ A, const bf16* __restrict__ W, int m0, int n0,
    bf16* __restrict__ out0, bf16* __restrict__ out1, float* __restrict__ outf)
{
    __shared__ __align__(16) bf16 sA[128 * 32];
    __shared__ __align__(16) bf16 sB[128 * 32];
    const int lane = threadIdx.x & 63;
    const int w = threadIdx.x >> 6;
    const int lr = lane & 15, quad = lane >> 4;
    const int m_off = (w & 1) * 64, n_off = (w >> 1) * 64;

    const int srow = lane >> 2;                     // row-in-16 of staged tile
    const int ssw  = (srow + (srow >> 2)) & 3;      // staging swizzle
    const bf16* ap = A + (size_t)(m0 + w * 32 + srow) * CDIM + (((lane & 3) ^ ssw)) * 8;
    const bf16* bp = W + (size_t)(n0 + w * 32 + srow) * CDIM + (((lane & 3) ^ ssw)) * 8;
    bf16* sA0 = &sA[(w * 32) * 32];
    bf16* sA1 = &sA[(w * 32 + 16) * 32];
    bf16* sB0 = &sB[(w * 32) * 32];
    bf16* sB1 = &sB[(w * 32 + 16) * 32];

    const int rsw = (lr + (lr >> 2)) & 3;           // read swizzle
    const int ccol = ((quad ^ rsw)) * 8;

    ffrag acc[4][4] = {};
    for (int kk = 0; kk < CDIM; kk += 32) {
        __syncthreads();
        stage16(ap, sA0, lane);
        stage16(ap + (size_t)16 * CDIM, sA1, lane);
        stage16(bp, sB0, lane);
        stage16(bp + (size_t)16 * CDIM, sB1, lane);
        ap += 32; bp += 32;
        __syncthreads();

        bfrag af[4], bg[4];
        #pragma unroll
        for (int s = 0; s < 4; ++s) af[s] = *(const bfrag*)&sA[(m_off + s * 16 + lr) * 32 + ccol];
        #pragma unroll
        for (int s = 0; s < 4; ++s) bg[s] = *(const bfrag*)&sB[(n_off + s * 16 + lr) * 32 + ccol];
        #pragma unroll
        for (int i = 0; i < 4; ++i)
            #pragma unroll
            for (int j = 0; j < 4; ++j)
                acc[i][j] = __builtin_amdgcn_mfma_f32_16x16x32_bf16(af[i], bg[j], acc[i][j], 0, 0, 0);
    }

    #pragma unroll
    for (int si = 0; si < 4; ++si) {
        #pragma unroll
        for (int sj = 0; sj < 4; ++sj) {
            #pragma unroll
            for (int i = 0; i < 4; ++i) {
                int m = m0 + m_off + si * 16 + quad * 4 + i;
                int n = n0 + n_off + sj * 16 + lr;
                float v = acc[si][sj][i];
                if (MODE == 0) {
                    int b = m >> 11, t = m & (T_SEQ - 1);
                    int h = n >> 7, d = n & (DH - 1);
                    out0[(((size_t)(b * NH + h) * T_SEQ + t) << 7) + d] = __float2bfloat16(v);
                } else if (MODE == 1) {
                    int b = m >> 11, t = m & (T_SEQ - 1);
                    if (n < NKV * DH) {
                        int h = n >> 7, d = n & (DH - 1);
                        out0[(((size_t)(b * NKV + h) * T_SEQ + t) << 7) + d] = __float2bfloat16(v);
                    } else {
                        int n2 = n - NKV * DH;
                        int h = n2 >> 7, d = n2 & (DH - 1);
                        out1[(((size_t)(b * NKV + h) * DH + d) << 11) + t] = __float2bfloat16(v);
                    }
                } else {
                    outf[(size_t)m * CDIM + n] = v;
                }
            }
        }
    }
}

__global__ __launch_bounds__(256) void gemm_qkv(
    const bf16* __restrict__ A, const bf16* __restrict__ Wq, const bf16* __restrict__ Wkv,
    bf16* __restrict__ q, bf16* __restrict__ k, bf16* __restrict__ vt)
{
    if (blockIdx.y < 16)
        gemm_body<0>(A, Wq, blockIdx.x * 128, blockIdx.y * 128, q, nullptr, nullptr);
    else
        gemm_body<1>(A, Wkv, blockIdx.x * 128, (blockIdx.y - 16) * 128, k, vt, nullptr);
}

__global__ __launch_bounds__(256) void gemm_proj(
    const bf16* __restrict__ A, const bf16* __restrict__ W, float* __restrict__ outf)
{
    gemm_body<2>(A, W, blockIdx.x * 128, blockIdx.y * 128, nullptr, nullptr, outf);
    if (blockIdx.x == 0 && blockIdx.y == 0 && threadIdx.x == 0)
        outf[(size_t)BATCH * T_SEQ * CDIM] = 0.0f;   // reference's second output: 0.0
}

// ---------------- RMSNorm + rotary, q and k fused in one launch ----------------
#define QROWS (BATCH * NH * T_SEQ)
#define KROWS (BATCH * NKV * T_SEQ)
__global__ __launch_bounds__(256) void normrope_k(bf16* __restrict__ qb, bf16* __restrict__ kb) {
    int row = blockIdx.x * 4 + (threadIdx.x >> 6);
    bf16* bufb; int nheads;
    if (row < QROWS) { bufb = qb; nheads = NH; }
    else { row -= QROWS; bufb = kb; nheads = NKV; }
    const int h = (row >> 11) % nheads;            // T = 2^11; angle uses HEAD idx (per ref)
    bf16* p = bufb + (size_t)row * DH;
    const int d = threadIdx.x & 63;
    float x1 = __bfloat162float(p[d]);
    float x2 = __bfloat162float(p[d + 64]);
    float ss = x1 * x1 + x2 * x2;
    #pragma unroll
    for (int off = 32; off; off >>= 1) ss += __shfl_xor(ss, off);
    float r = rsqrtf(ss * (1.0f / 128.0f) + 1.1920929e-07f);
    x1 *= r; x2 *= r;
    float freq = (d < 32) ? exp2f(-10.0f * (float)d * (1.0f / 31.0f)) : 0.0f;
    float th = (float)h * freq;
    float c, s;
    __sincosf(th, &s, &c);
    p[d]      = __float2bfloat16(x1 * c + x2 * s);
    p[d + 64] = __float2bfloat16(-x1 * s + x2 * c);
}

// ---------------- Flash attention v5: 8 waves, even/odd chunk groups ----------------
// Static-max softmax (RMS-normed q,k => |score*scale| <= 11.32; exp(s-16) exact).
// Block = 512 thr: group g = waves 0-3 / 4-7; both groups cover the same 128 q-rows
// (wave wl -> rows qb*128 + wl*32, two 16-row tiles) but disjoint 32-key chunks
// (abs chunk 2c+g). Partial (O, l) add linearly (static max) -> fp32 LDS merge.
// Pass pairing (p, 15-p) => uniform 34 group-chunks/block. All LDS arrays are
// unpadded with XOR-chunk swizzle => every access <=2-way (free).
__global__ __launch_bounds__(512, 2) void attn_k(const bf16* __restrict__ Q, const bf16* __restrict__ K,
                                                 const bf16* __restrict__ VT, bf16* __restrict__ Y)
{
    const int lane = threadIdx.x & 63;
    const int w = threadIdx.x >> 6;          // 0..7
    const int g = w >> 2, wl = w & 3;
    const int p = blockIdx.x, h = blockIdx.y, b = blockIdx.z;
    const int lr = lane & 15, quad = lane >> 4, lk = quad * 8;
    const bf16* Qb = Q  + (size_t)(b * NH  + h)        * T_SEQ * DH;
    const bf16* Kb = K  + (size_t)(b * NKV + (h >> 2)) * T_SEQ * DH;
    const bf16* Vb = VT + (size_t)(b * NKV + (h >> 2)) * DH * T_SEQ;

    __shared__ __align__(16) union ShmU {
        struct { bf16 SK[2][32 * 128]; bf16 SV[2][128 * 32]; bf16 SP[8][2][16 * 32]; } s;
        ffrag MRG[9 * 4 * 64];               // 36864 B merge area (aliases SK/SV/SP)
    } shm;
    bf16* SKg = shm.s.SK[g];
    bf16* SVg = shm.s.SV[g];

    // staging coords: K chunk 32(keys)x128, V chunk 128(d)x32(keys), per group
    const int k_r0 = wl * 8 + (lane >> 4);   // + j*4
    const int k_ch = lane & 15;
    const int v_r0 = wl * 32 + (lane >> 2);  // + j*16
    const int v_ch = lane & 3;
    const int vsw = (lr + (lr >> 2)) & 3;    // SV read swizzle (row = dt*16+lr)
    const int prow_r = ((lr & 3) << 2) | (lr >> 2);      // P physical row for read
    const int psw = (prow_r + (prow_r >> 2)) & 3;
    const float scale = 0.08838834764831845f;            // 1/sqrt(128)

    for (int pass = 0; pass < 2; ++pass) {
        const int qb = pass ? (15 - p) : p;
        const int nc = 2 * (qb + 1);         // 32-key chunks for THIS group
        const int q0 = qb * 128 + wl * 32;

        bfrag qf[2][4];
        #pragma unroll
        for (int t = 0; t < 2; ++t)
            #pragma unroll
            for (int dc = 0; dc < 4; ++dc)
                qf[t][dc] = *(const bfrag*)(Qb + (size_t)(q0 + t * 16 + lr) * DH + dc * 32 + lk);

        float lp[2][4] = {};
        ffrag o[2][8] = {};

        bfrag kr[2], vr[2];                  // prefetch chunk 0 (abs chunk g)
        {
            const int b0 = g * 32;
            #pragma unroll
            for (int j = 0; j < 2; ++j) {
                kr[j] = *(const bfrag*)(Kb + (size_t)(b0 + k_r0 + j * 4) * DH + k_ch * 8);
                vr[j] = *(const bfrag*)(Vb + (size_t)(v_r0 + j * 16) * T_SEQ + b0 + v_ch * 8);
            }
        }

        for (int c = 0; c < nc; ++c) {
            const int base = c * 64 + g * 32;
            __syncthreads();                 // all waves done reading SK/SV (and MRG)
            #pragma unroll
            for (int j = 0; j < 2; ++j) {
                int krow = k_r0 + j * 4;
                *(bfrag*)&SKg[krow * 128 + ((k_ch ^ (krow & 15))) * 8] = kr[j];
                int vrow = v_r0 + j * 16;
                *(bfrag*)&SVg[vrow * 32 + ((v_ch ^ ((vrow + (vrow >> 2)) & 3))) * 8] = vr[j];
            }
            if (c + 1 < nc) {                // prefetch next; stays in flight across barrier
                const int nb = base + 64;
                #pragma unroll
                for (int j = 0; j < 2; ++j) {
                    kr[j] = *(const bfrag*)(Kb + (size_t)(nb + k_r0 + j * 4) * DH + k_ch * 8);
                    vr[j] = *(const bfrag*)(Vb + (size_t)(v_r0 + j * 16) * T_SEQ + nb + v_ch * 8);
                }
            }
            __syncthreads();                 // staged data visible

            // QK^T: each kf feeds both row-tiles
            ffrag s2[2][2] = {};
            #pragma unroll
            for (int kt = 0; kt < 2; ++kt)
                #pragma unroll
                for (int dc = 0; dc < 4; ++dc) {
                    bfrag kf = *(const bfrag*)&SKg[(kt * 16 + lr) * 128 + (((dc << 2) | quad) ^ lr) * 8];
                    s2[0][kt] = __builtin_amdgcn_mfma_f32_16x16x32_bf16(qf[0][dc], kf, s2[0][kt], 0, 0, 0);
                    s2[1][kt] = __builtin_amdgcn_mfma_f32_16x16x32_bf16(qf[1][dc], kf, s2[1][kt], 0, 0, 0);
                }

            // softmax numerator (static max); P -> LDS, rows 4x4-transposed, chunks swizzled
            const bool maskc = (c >= 2 * qb);
            #pragma unroll
            for (int t = 0; t < 2; ++t)
                #pragma unroll
                for (int kt = 0; kt < 2; ++kt) {
                    const int col = base + kt * 16 + lr;
                    #pragma unroll
                    for (int i = 0; i < 4; ++i) {
                        const int row = q0 + t * 16 + quad * 4 + i;
                        float e = (!maskc || col <= row) ? __expf(fmaf(s2[t][kt][i], scale, -16.0f)) : 0.0f;
                        lp[t][i] += e;
                        const int pr = i * 4 + quad;
                        const int pc = (kt * 2 + (lr >> 3)) ^ ((quad + i) & 3);
                        shm.s.SP[w][t][pr * 32 + pc * 8 + (lr & 7)] = __float2bfloat16(e);
                    }
                }

            // P.V: each vf feeds both row-tiles (per-wave SP: lgkmcnt handles RAW)
            bfrag pf0 = *(const bfrag*)&shm.s.SP[w][0][prow_r * 32 + ((quad ^ psw)) * 8];
            bfrag pf1 = *(const bfrag*)&shm.s.SP[w][1][prow_r * 32 + ((quad ^ psw)) * 8];
            #pragma unroll
            for (int dt = 0; dt < 8; ++dt) {
                bfrag vf = *(const bfrag*)&SVg[(dt * 16 + lr) * 32 + ((quad ^ vsw)) * 8];
                o[0][dt] = __builtin_amdgcn_mfma_f32_16x16x32_bf16(pf0, vf, o[0][dt], 0, 0, 0);
                o[1][dt] = __builtin_amdgcn_mfma_f32_16x16x32_bf16(pf1, vf, o[1][dt], 0, 0, 0);
            }
        }

        // merge groups (fp32, two rounds to fit LDS) + epilogue by group 0
        __syncthreads();
        #pragma unroll
        for (int t = 0; t < 2; ++t) {
            if (g == 1) {
                #pragma unroll
                for (int d = 0; d < 8; ++d) shm.MRG[(d * 4 + wl) * 64 + lane] = o[t][d];
                ffrag l4 = {lp[t][0], lp[t][1], lp[t][2], lp[t][3]};
                shm.MRG[(8 * 4 + wl) * 64 + lane] = l4;
            }
            __syncthreads();
            if (g == 0) {
                #pragma unroll
                for (int d = 0; d < 8; ++d) o[t][d] += shm.MRG[(d * 4 + wl) * 64 + lane];
                ffrag l4 = shm.MRG[(8 * 4 + wl) * 64 + lane];
                float inv[4];
                #pragma unroll
                for (int i = 0; i < 4; ++i) {
                    float l = lp[t][i] + l4[i];
                    #pragma unroll
                    for (int off = 1; off < 16; off <<= 1) l += __shfl_xor(l, off);
                    inv[i] = 1.0f / l;
                }
                #pragma unroll
                for (int dt = 0; dt < 8; ++dt)
                    #pragma unroll
                    for (int i = 0; i < 4; ++i) {
                        int row = q0 + t * 16 + quad * 4 + i;
                        Y[((size_t)(b * T_SEQ) + row) * CDIM + h * DH + dt * 16 + lr] =
                            __float2bfloat16(o[t][dt][i] * inv[i]);
                    }
            }
            __syncthreads();                 // protect MRG before next round / next pass
        }
    }
}

extern "C" void kernel_launch(void* const* d_in, const int* in_sizes, int n_in,
                              void* d_out, int out_size, void* d_ws, size_t ws_size,
                              hipStream_t stream) {
    const float* x     = (const float*)d_in[0];
    const float* Wq    = (const float*)d_in[1];
    const float* Wkv   = (const float*)d_in[2];
    const float* Wproj = (const float*)d_in[3];
    float* out = (float*)d_out;

    char* ws = (char*)d_ws;
    size_t off = 0;
    auto alloc = [&](size_t bytes) { void* p = ws + off; off += (bytes + 255) & ~255ULL; return p; };
    bf16* xb   = (bf16*)alloc((size_t)BATCH * T_SEQ * CDIM * 2);
    bf16* wqb  = (bf16*)alloc((size_t)CDIM * CDIM * 2);
    bf16* wkvb = (bf16*)alloc((size_t)2 * NKV * DH * CDIM * 2);
    bf16* wpb  = (bf16*)alloc((size_t)CDIM * CDIM * 2);
    bf16* qb   = (bf16*)alloc((size_t)BATCH * NH * T_SEQ * DH * 2);
    bf16* kb   = (bf16*)alloc((size_t)BATCH * NKV * T_SEQ * DH * 2);
    bf16* vtb  = (bf16*)alloc((size_t)BATCH * NKV * DH * T_SEQ * 2);
    bf16* y1   = (bf16*)alloc((size_t)BATCH * T_SEQ * CDIM * 2);

    const int total4 = N4_X + N4_WQ + N4_WKV + N4_WP;
    cast_all<<<(total4 + 255) / 256, 256, 0, stream>>>(x, Wq, Wkv, Wproj, xb, wqb, wkvb, wpb);

    gemm_qkv<<<dim3(32, 24), 256, 0, stream>>>(xb, wqb, wkvb, qb, kb, vtb);
    normrope_k<<<(QROWS + KROWS) / 4, 256, 0, stream>>>(qb, kb);
    attn_k<<<dim3(8, NH, BATCH), 512, 0, stream>>>(qb, kb, vtb, y1);
    gemm_proj<<<dim3(32, 16), 256, 0, stream>>>(y1, wpb, out);
}